// Round 15
// baseline (1622.666 us; speedup 1.0000x reference)
//
#include <hip/hip_runtime.h>
#include <hip/hip_bf16.h>
#include <math.h>

#define MQ   65536
#define OUTD 128

typedef __attribute__((ext_vector_type(8))) short bf16x8;
typedef __attribute__((ext_vector_type(4))) short bf16x4;
typedef __attribute__((ext_vector_type(4))) float f32x4;

// ws byte offsets (bf16 weights + folded pos params)
#define WS_QKV   0        // 2*192*64 bf16 = 49152B
#define WS_AOW   49152    // 2*64*64       = 16384B
#define WS_F1W   65536    // 2*128*64      = 32768B
#define WS_F2W   98304    // 2*64*128      = 32768B
#define WS_PW2   131072   // 64*32         = 4096B
#define WS_W1F   135168   // 32*3 f32      = 384B
#define WS_PBF   135552   // 32 f32        = 128B

__device__ __forceinline__ unsigned short f2bf(float f) {
  unsigned u = __float_as_uint(f);
  u = (u + 0x7FFFu + ((u >> 16) & 1u)) >> 16;   // RTN
  return (unsigned short)u;
}

__device__ __forceinline__ f32x4 mfma16(bf16x8 a, bf16x8 b, f32x4 c) {
  return __builtin_amdgcn_mfma_f32_16x16x32_bf16(a, b, c, 0, 0, 0);
}

__device__ __forceinline__ unsigned pk2(float a, float b) {
  union { __hip_bfloat162 h; unsigned u; } c;
  float2 p; p.x = a; p.y = b;
  c.h = __float22bfloat162_rn(p);
  return c.u;
}

__device__ __forceinline__ bf16x4 pack4(f32x4 v) {
  union { unsigned u[2]; bf16x4 s; } c;
  c.u[0] = pk2(v[0], v[1]);
  c.u[1] = pk2(v[2], v[3]);
  return c.s;
}

__device__ __forceinline__ bf16x8 pack8(const float* v) {
  union { unsigned u[4]; bf16x8 s; } c;
#pragma unroll
  for (int i = 0; i < 4; i++) c.u[i] = pk2(v[2*i], v[2*i+1]);
  return c.s;
}

// Opaque compiler fence: pins LDS reads above / writes below (same-wave ordering).
__device__ __forceinline__ void cfence() { asm volatile("" ::: "memory"); }

// ---------------- weight conversion prologue (unchanged, round-2-verified) ----------------
extern "C" __global__ __launch_bounds__(256)
void convert_weights(const float* __restrict__ qkv_w, const float* __restrict__ aow,
                     const float* __restrict__ f1w,  const float* __restrict__ f2w,
                     const float* __restrict__ pw2,  const float* __restrict__ pw1,
                     const float* __restrict__ png,  const float* __restrict__ pnb,
                     const float* __restrict__ pnm,  const float* __restrict__ pnv,
                     unsigned char* __restrict__ ws) {
  int i = blockIdx.x * 256 + threadIdx.x;
  if (i < 24576) {
    ((unsigned short*)(ws + WS_QKV))[i] = f2bf(qkv_w[i]);
  } else if (i < 32768) {
    int j = i - 24576; ((unsigned short*)(ws + WS_AOW))[j] = f2bf(aow[j]);
  } else if (i < 49152) {
    int j = i - 32768; ((unsigned short*)(ws + WS_F1W))[j] = f2bf(f1w[j]);
  } else if (i < 65536) {
    int j = i - 49152; ((unsigned short*)(ws + WS_F2W))[j] = f2bf(f2w[j]);
  } else if (i < 67584) {
    int j = i - 65536; ((unsigned short*)(ws + WS_PW2))[j] = f2bf(pw2[j]);
  } else if (i < 67616) {
    int k = i - 67584;
    float s = png[k] * rsqrtf(pnv[k] + 1e-5f);
    float* w1f = (float*)(ws + WS_W1F);
    float* pbf = (float*)(ws + WS_PBF);
    w1f[k*3+0] = pw1[k*3+0] * s;
    w1f[k*3+1] = pw1[k*3+1] * s;
    w1f[k*3+2] = pw1[k*3+2] * s;
    pbf[k] = pnb[k] - pnm[k] * s;
  }
}

// ---------------- main fused kernel: 1 group / block, 2 waves, residual x in registers ----------------
// x[nt][mi][r] = X[ch = (w+mi*2)*16 + hi*4 + r][tok = nt*16 + lr]
// Round-15: Q never touches LDS (own-token Q tiles + register shuffle into the
// scores B-fragment, same verified pattern as the P redistribution). A2 reuses
// the S arena; Fb spans Kb+Vt; lnbuf gets a dedicated tail. LDS 18944 -> 14848B
// => 10-11 blocks/CU (was 8).
extern "C" __global__ __launch_bounds__(128, 2)
void nvt_mfma(const float* __restrict__ xyz,
              const float* __restrict__ new_xyz,
              const float* __restrict__ features,
              const int* __restrict__ group_idx,
              const unsigned char* __restrict__ empty_mask,
              const float* __restrict__ pos_b2,
              const float* __restrict__ ln1_g, const float* __restrict__ ln1_b,
              const float* __restrict__ qkv_b,
              const float* __restrict__ aob,
              const float* __restrict__ ln2_g, const float* __restrict__ ln2_b,
              const float* __restrict__ f1b,
              const float* __restrict__ f2b,
              const float* __restrict__ out_w, const float* __restrict__ out_b,
              const unsigned char* __restrict__ ws,
              float* __restrict__ out) {
  // LDS 14848B:
  //   S  @0     [32][72] bf16  (alias Hs[32][40], A2[32][72], part f32[2][64])
  //   Kb @4608  [32][72]       (Fb[32][136] spans Kb+Vt, dead when Fb live)
  //   Vt @9216  [64][40]
  //   lnbuf @14336  f32[2][32][2] (dedicated, no aliasing)
  __shared__ __align__(16) unsigned char smem[14848];
  unsigned short* S  = (unsigned short*)smem;
  unsigned short* Kb = (unsigned short*)(smem + 4608);
  unsigned short* Fb = (unsigned short*)(smem + 4608);   // stride 136, spans Kb+Vt
  unsigned short* Vt = (unsigned short*)(smem + 9216);   // [64][40]
  unsigned short* Hs = S;                                // h staging [32][40]
  unsigned short* A2 = S;                                // attn result [32][72]
  float*          part  = (float*)smem;                  // [2][64]
  float*          lnbuf = (float*)(smem + 14336);        // [2][32][2]

  const unsigned short* qkvw_b = (const unsigned short*)(ws + WS_QKV);
  const unsigned short* aow_b  = (const unsigned short*)(ws + WS_AOW);
  const unsigned short* f1w_b  = (const unsigned short*)(ws + WS_F1W);
  const unsigned short* f2w_b  = (const unsigned short*)(ws + WS_F2W);
  const unsigned short* w2b    = (const unsigned short*)(ws + WS_PW2);
  const float* w1f = (const float*)(ws + WS_W1F);
  const float* pbf = (const float*)(ws + WS_PBF);

  const int m    = blockIdx.x;
  const int tid  = threadIdx.x;
  const int w    = tid >> 6;       // wave 0/1
  const int lane = tid & 63;
  const int lr   = lane & 15;
  const int hi   = lane >> 4;
  const bool empty = empty_mask[m] != 0;

  // ---- stage A: h -> Hs ; gather features into x registers ----
  {
    int t = tid & 31, kb = tid >> 5;
    int idx = group_idx[m * 32 + t];
    float g0 = xyz[idx*3+0] - new_xyz[m*3+0];
    float g1 = xyz[idx*3+1] - new_xyz[m*3+1];
    float g2 = xyz[idx*3+2] - new_xyz[m*3+2];
    if (empty) { g0 = 0.f; g1 = 0.f; g2 = 0.f; }
    float hf[8];
#pragma unroll
    for (int j = 0; j < 8; j++) {
      int k = kb * 8 + j;
      float hp = fmaf(g0, w1f[k*3+0], fmaf(g1, w1f[k*3+1], g2 * w1f[k*3+2])) + pbf[k];
      hf[j] = fmaxf(hp, 0.f);
    }
    *(bf16x8*)&Hs[t * 40 + kb * 8] = pack8(hf);
  }
  f32x4 x[2][2];
  {
    int tg[2];
    tg[0] = group_idx[m * 32 + lr];
    tg[1] = group_idx[m * 32 + 16 + lr];
#pragma unroll
    for (int nt = 0; nt < 2; nt++)
#pragma unroll
      for (int mi = 0; mi < 2; mi++) {
        int mt = w + mi * 2;
        x[nt][mi] = *(const f32x4*)(features + (size_t)tg[nt] * 64 + mt * 16 + hi * 4);
      }
    if (empty) {
#pragma unroll
      for (int nt = 0; nt < 2; nt++)
#pragma unroll
        for (int mi = 0; mi < 2; mi++) { x[nt][mi][0]=0.f; x[nt][mi][1]=0.f; x[nt][mi][2]=0.f; x[nt][mi][3]=0.f; }
    }
  }
  __syncthreads();

  // ---- pos MLP layer 2 via MFMA: x += h @ w2^T + b2 ----
  {
    bf16x8 bh[2];
#pragma unroll
    for (int nt = 0; nt < 2; nt++)
      bh[nt] = *(const bf16x8*)&Hs[(nt * 16 + lr) * 40 + hi * 8];
    __builtin_amdgcn_s_setprio(1);
#pragma unroll
    for (int mi = 0; mi < 2; mi++) {
      int mt = w + mi * 2;
      bf16x8 a = *(const bf16x8*)(w2b + (mt * 16 + lr) * 32 + hi * 8);
      float4 b4 = *(const float4*)(pos_b2 + mt * 16 + hi * 4);
      f32x4 bias; bias[0] = b4.x; bias[1] = b4.y; bias[2] = b4.z; bias[3] = b4.w;
#pragma unroll
      for (int nt = 0; nt < 2; nt++) x[nt][mi] += mfma16(a, bh[nt], bias);
    }
    __builtin_amdgcn_s_setprio(0);
  }
  // (no barrier: LN's internal barrier separates Hs reads from S writes)

  // LN: x regs -> S (bf16), cross-wave partial-sum exchange through lnbuf
  auto LN = [&](const float* g, const float* b) {
    float s[2], s2[2];
#pragma unroll
    for (int nt = 0; nt < 2; nt++) {
      float a = 0.f, a2 = 0.f;
#pragma unroll
      for (int mi = 0; mi < 2; mi++)
#pragma unroll
        for (int r = 0; r < 4; r++) { float v = x[nt][mi][r]; a += v; a2 = fmaf(v, v, a2); }
      a  += __shfl_xor(a, 16);  a  += __shfl_xor(a, 32);
      a2 += __shfl_xor(a2, 16); a2 += __shfl_xor(a2, 32);
      s[nt] = a; s2[nt] = a2;
    }
    if (hi == 0) {
#pragma unroll
      for (int nt = 0; nt < 2; nt++) {
        int tok = nt * 16 + lr;
        lnbuf[w * 64 + tok * 2 + 0] = s[nt];
        lnbuf[w * 64 + tok * 2 + 1] = s2[nt];
      }
    }
    __syncthreads();
#pragma unroll
    for (int nt = 0; nt < 2; nt++) {
      int tok = nt * 16 + lr;
      float st  = s[nt]  + lnbuf[(1 - w) * 64 + tok * 2 + 0];
      float s2t = s2[nt] + lnbuf[(1 - w) * 64 + tok * 2 + 1];
      float mu  = st * (1.f/64.f);
      float var = s2t * (1.f/64.f) - mu * mu;
      float inv = rsqrtf(fmaxf(var, 0.f) + 1e-5f);
#pragma unroll
      for (int mi = 0; mi < 2; mi++) {
        int mt = w + mi * 2;
        float4 g4 = *(const float4*)(g + mt * 16 + hi * 4);
        float4 b4 = *(const float4*)(b + mt * 16 + hi * 4);
        f32x4 o;
        o[0] = fmaf((x[nt][mi][0] - mu) * inv, g4.x, b4.x);
        o[1] = fmaf((x[nt][mi][1] - mu) * inv, g4.y, b4.y);
        o[2] = fmaf((x[nt][mi][2] - mu) * inv, g4.z, b4.z);
        o[3] = fmaf((x[nt][mi][3] - mu) * inv, g4.w, b4.w);
        *(bf16x4*)&S[tok * 72 + mt * 16 + hi * 4] = pack4(o);
      }
    }
    __syncthreads();
  };

  // ---- transformer layers ----
  for (int ly = 0; ly < 2; ly++) {
    LN(ln1_g + ly*64, ln1_b + ly*64);

    bf16x8 bq[2];   // Q B-fragment for scores, built in registers (carried across barrier)

    // qkv: Q all-4-tiles for OWN token tile (registers); K tiles {4+w,6+w} -> Kb;
    //      V swapped -> Vt
    {
      bf16x8 bs[2][2];
#pragma unroll
      for (int nt = 0; nt < 2; nt++)
#pragma unroll
        for (int kt = 0; kt < 2; kt++)
          bs[nt][kt] = *(const bf16x8*)&S[(nt * 16 + lr) * 72 + kt * 32 + hi * 8];
      bf16x8 bsq[2];   // own token rows (avoid runtime-indexing bs by w — rule #20)
#pragma unroll
      for (int kt = 0; kt < 2; kt++)
        bsq[kt] = *(const bf16x8*)&S[(w * 16 + lr) * 72 + kt * 32 + hi * 8];
      const unsigned short* Wq = qkvw_b + ly * 192 * 64;
      const float* Bq = qkv_b + ly * 192;

      __builtin_amdgcn_s_setprio(1);
      // Q: acc[r] = Q[ch=mt*16+hi*4+r][tok=w*16+lr]
      unsigned qa[4][2];
#pragma unroll
      for (int mt = 0; mt < 4; mt++) {
        bf16x8 a0 = *(const bf16x8*)(Wq + (mt * 16 + lr) * 64 + hi * 8);
        bf16x8 a1 = *(const bf16x8*)(Wq + (mt * 16 + lr) * 64 + 32 + hi * 8);
        float4 b4 = *(const float4*)(Bq + mt * 16 + hi * 4);
        f32x4 acc; acc[0] = b4.x; acc[1] = b4.y; acc[2] = b4.z; acc[3] = b4.w;
        acc = mfma16(a0, bsq[0], acc);
        acc = mfma16(a1, bsq[1], acc);
        qa[mt][0] = pk2(acc[0], acc[1]);
        qa[mt][1] = pk2(acc[2], acc[3]);
      }
      // K: tiles kc = w, w+2 (weight rows 64 + kc*16 ...), both token tiles -> Kb
#pragma unroll
      for (int mi = 0; mi < 2; mi++) {
        int kc = w + mi * 2;
        bf16x8 a0 = *(const bf16x8*)(Wq + ((4 + kc) * 16 + lr) * 64 + hi * 8);
        bf16x8 a1 = *(const bf16x8*)(Wq + ((4 + kc) * 16 + lr) * 64 + 32 + hi * 8);
        float4 b4 = *(const float4*)(Bq + 64 + kc * 16 + hi * 4);
#pragma unroll
        for (int nt = 0; nt < 2; nt++) {
          f32x4 acc; acc[0] = b4.x; acc[1] = b4.y; acc[2] = b4.z; acc[3] = b4.w;
          acc = mfma16(a0, bs[nt][0], acc);
          acc = mfma16(a1, bs[nt][1], acc);
          *(bf16x4*)&Kb[(nt * 16 + lr) * 72 + kc * 16 + hi * 4] = pack4(acc);
        }
      }
      // V swapped: acc[r] = V[tok=nt*16+hi*4+r][ch=mtv*16+lr]
#pragma unroll
      for (int mvi = 0; mvi < 2; mvi++) {
        int mtv = w + mvi * 2;
        bf16x8 b0 = *(const bf16x8*)(Wq + (128 + mtv * 16 + lr) * 64 + hi * 8);
        bf16x8 b1 = *(const bf16x8*)(Wq + (128 + mtv * 16 + lr) * 64 + 32 + hi * 8);
        float bv = Bq[128 + mtv * 16 + lr];
#pragma unroll
        for (int nt = 0; nt < 2; nt++) {
          f32x4 acc; acc[0] = bv; acc[1] = bv; acc[2] = bv; acc[3] = bv;
          acc = mfma16(bs[nt][0], b0, acc);
          acc = mfma16(bs[nt][1], b1, acc);
          *(bf16x4*)&Vt[(mtv * 16 + lr) * 40 + nt * 16 + hi * 4] = pack4(acc);
        }
      }
      __builtin_amdgcn_s_setprio(0);

      // Q redistribution -> bq[kt] = Q[tok=w*16+lr][ch=kt*32+hi*8 .. +8]
      // src: mt = 2kt + (hi>>1); lanes (lr, 2(hi&1)) and (lr, 2(hi&1)+1)
      {
        int sh1 = lr + 32 * (hi & 1);
        int sh2 = sh1 + 16;
        unsigned A_[4][2], B_[4][2];
#pragma unroll
        for (int mt = 0; mt < 4; mt++)
#pragma unroll
          for (int sidx = 0; sidx < 2; sidx++) {
            A_[mt][sidx] = __shfl(qa[mt][sidx], sh1);
            B_[mt][sidx] = __shfl(qa[mt][sidx], sh2);
          }
        bool sel = (hi >> 1) != 0;
        union { unsigned uu[4]; bf16x8 v; } q0, q1;
        q0.uu[0] = sel ? A_[1][0] : A_[0][0];
        q0.uu[1] = sel ? A_[1][1] : A_[0][1];
        q0.uu[2] = sel ? B_[1][0] : B_[0][0];
        q0.uu[3] = sel ? B_[1][1] : B_[0][1];
        q1.uu[0] = sel ? A_[3][0] : A_[2][0];
        q1.uu[1] = sel ? A_[3][1] : A_[2][1];
        q1.uu[2] = sel ? B_[3][0] : B_[2][0];
        q1.uu[3] = sel ? B_[3][1] : B_[2][1];
        bq[0] = q0.v;
        bq[1] = q1.v;
      }
    }
    __syncthreads();   // publish Kb, Vt

    // ---- fused scores + softmax + PV (own i-tile = own token-tile w; Q from registers) ----
    {
      bf16x8 ak[2][2], av[4];
#pragma unroll
      for (int jt = 0; jt < 2; jt++)
#pragma unroll
        for (int kt = 0; kt < 2; kt++)
          ak[jt][kt] = *(const bf16x8*)&Kb[(jt * 16 + lr) * 72 + kt * 32 + hi * 8];
#pragma unroll
      for (int mt = 0; mt < 4; mt++)
        av[mt] = *(const bf16x8*)&Vt[(mt * 16 + lr) * 40 + hi * 8];
      cfence();

      // scores: p[jt][r] = P[j=jt*16+hi*4+r][i=w*16+lr]
      __builtin_amdgcn_s_setprio(1);
      f32x4 p[2];
#pragma unroll
      for (int jt = 0; jt < 2; jt++) {
        f32x4 acc; acc[0] = 0.f; acc[1] = 0.f; acc[2] = 0.f; acc[3] = 0.f;
#pragma unroll
        for (int kt = 0; kt < 2; kt++) acc = mfma16(ak[jt][kt], bq[kt], acc);
        p[jt] = acc;
      }
      __builtin_amdgcn_s_setprio(0);
      float mx = -3.4e38f;
#pragma unroll
      for (int jt = 0; jt < 2; jt++)
#pragma unroll
        for (int r = 0; r < 4; r++) { p[jt][r] *= 0.125f; mx = fmaxf(mx, p[jt][r]); }
      mx = fmaxf(mx, __shfl_xor(mx, 16));
      mx = fmaxf(mx, __shfl_xor(mx, 32));
      float sum = 0.f;
#pragma unroll
      for (int jt = 0; jt < 2; jt++)
#pragma unroll
        for (int r = 0; r < 4; r++) { float e = __expf(p[jt][r] - mx); p[jt][r] = e; sum += e; }
      sum += __shfl_xor(sum, 16);
      sum += __shfl_xor(sum, 32);
      float inv = 1.f / sum;

      // redistribute P to PV B-fragment layout via 8 shuffles (round-10-verified)
      unsigned u[2][2];
#pragma unroll
      for (int jt = 0; jt < 2; jt++) {
        u[jt][0] = pk2(p[jt][0] * inv, p[jt][1] * inv);
        u[jt][1] = pk2(p[jt][2] * inv, p[jt][3] * inv);
      }
      int s1 = lr + 32 * (hi & 1);
      int s2 = s1 + 16;
      unsigned c0 = __shfl(u[0][0], s1), c1 = __shfl(u[0][1], s1);
      unsigned d0 = __shfl(u[0][0], s2), d1 = __shfl(u[0][1], s2);
      unsigned e0 = __shfl(u[1][0], s1), e1 = __shfl(u[1][1], s1);
      unsigned f0 = __shfl(u[1][0], s2), f1 = __shfl(u[1][1], s2);
      bool sel = (hi >> 1) != 0;
      union { unsigned uu[4]; bf16x8 v; } bp;
      bp.uu[0] = sel ? e0 : c0;
      bp.uu[1] = sel ? e1 : c1;
      bp.uu[2] = sel ? f0 : d0;
      bp.uu[3] = sel ? f1 : d1;

      // PV: D[ch][own tok tile] -> A2 (= S arena; S dead since qkv bs reads, barrier-separated)
      __builtin_amdgcn_s_setprio(1);
#pragma unroll
      for (int mt = 0; mt < 4; mt++) {
        f32x4 acc; acc[0] = 0.f; acc[1] = 0.f; acc[2] = 0.f; acc[3] = 0.f;
        acc = mfma16(av[mt], bp.v, acc);
        *(bf16x4*)&A2[(w * 16 + lr) * 72 + mt * 16 + hi * 4] = pack4(acc);
      }
      __builtin_amdgcn_s_setprio(0);
    }
    __syncthreads();   // publish A2

    // attn_out: x += A2 @ Wao^T + b (accumulate in registers)
    {
      bf16x8 ba[2][2];
#pragma unroll
      for (int nt = 0; nt < 2; nt++)
#pragma unroll
        for (int kt = 0; kt < 2; kt++)
          ba[nt][kt] = *(const bf16x8*)&A2[(nt * 16 + lr) * 72 + kt * 32 + hi * 8];
      const unsigned short* Wo = aow_b + ly * 64 * 64;
      const float* Bo = aob + ly * 64;
      __builtin_amdgcn_s_setprio(1);
#pragma unroll
      for (int mi = 0; mi < 2; mi++) {
        int mt = w + mi * 2;
        bf16x8 a[2];
#pragma unroll
        for (int kt = 0; kt < 2; kt++)
          a[kt] = *(const bf16x8*)(Wo + (mt * 16 + lr) * 64 + kt * 32 + hi * 8);
        float4 b4 = *(const float4*)(Bo + mt * 16 + hi * 4);
#pragma unroll
        for (int nt = 0; nt < 2; nt++) {
          f32x4 acc; acc[0] = b4.x; acc[1] = b4.y; acc[2] = b4.z; acc[3] = b4.w;
#pragma unroll
          for (int kt = 0; kt < 2; kt++) acc = mfma16(a[kt], ba[nt][kt], acc);
          x[nt][mi] += acc;
        }
      }
      __builtin_amdgcn_s_setprio(0);
    }
    // (no barrier: LN2's internal barrier separates A2 reads from S rewrites)

    LN(ln2_g + ly*64, ln2_b + ly*64);

    // ff1: F[t][o] = relu(S @ W1^T + b1) -> Fb (spans Kb+Vt, both dead)
    {
      bf16x8 bs[2][2];
#pragma unroll
      for (int nt = 0; nt < 2; nt++)
#pragma unroll
        for (int kt = 0; kt < 2; kt++)
          bs[nt][kt] = *(const bf16x8*)&S[(nt * 16 + lr) * 72 + kt * 32 + hi * 8];
      const unsigned short* W1 = f1w_b + ly * 128 * 64;
      const float* B1 = f1b + ly * 128;
      __builtin_amdgcn_s_setprio(1);
#pragma unroll
      for (int mi = 0; mi < 4; mi++) {
        int mt = w + mi * 2;
        bf16x8 a[2];
#pragma unroll
        for (int kt = 0; kt < 2; kt++)
          a[kt] = *(const bf16x8*)(W1 + (mt * 16 + lr) * 64 + kt * 32 + hi * 8);
        float4 b4 = *(const float4*)(B1 + mt * 16 + hi * 4);
#pragma unroll
        for (int nt = 0; nt < 2; nt++) {
          f32x4 acc; acc[0] = b4.x; acc[1] = b4.y; acc[2] = b4.z; acc[3] = b4.w;
#pragma unroll
          for (int kt = 0; kt < 2; kt++) acc = mfma16(a[kt], bs[nt][kt], acc);
#pragma unroll
          for (int r = 0; r < 4; r++) acc[r] = fmaxf(acc[r], 0.f);
          *(bf16x4*)&Fb[(nt * 16 + lr) * 136 + mt * 16 + hi * 4] = pack4(acc);
        }
      }
      __builtin_amdgcn_s_setprio(0);
    }
    __syncthreads();   // publish Fb

    // ff2: x += F @ W2^T + b2 (accumulate in registers)
    {
      bf16x8 bfr[2][4];
#pragma unroll
      for (int nt = 0; nt < 2; nt++)
#pragma unroll
        for (int kt = 0; kt < 4; kt++)
          bfr[nt][kt] = *(const bf16x8*)&Fb[(nt * 16 + lr) * 136 + kt * 32 + hi * 8];
      const unsigned short* W2 = f2w_b + ly * 64 * 128;
      const float* B2 = f2b + ly * 64;
      __builtin_amdgcn_s_setprio(1);
#pragma unroll
      for (int mi = 0; mi < 2; mi++) {
        int mt = w + mi * 2;
        bf16x8 a[4];
#pragma unroll
        for (int kt = 0; kt < 4; kt++)
          a[kt] = *(const bf16x8*)(W2 + (mt * 16 + lr) * 128 + kt * 32 + hi * 8);
        float4 b4 = *(const float4*)(B2 + mt * 16 + hi * 4);
#pragma unroll
        for (int nt = 0; nt < 2; nt++) {
          f32x4 acc; acc[0] = b4.x; acc[1] = b4.y; acc[2] = b4.z; acc[3] = b4.w;
#pragma unroll
          for (int kt = 0; kt < 4; kt++) acc = mfma16(a[kt], bfr[nt][kt], acc);
          x[nt][mi] += acc;
        }
      }
      __builtin_amdgcn_s_setprio(0);
    }
    // (no barrier: next LN1's internal barrier separates Fb reads from Kb/S rewrites;
    //  lnbuf is a dedicated region outside Fb)
  }

  // ---- max pool over tokens: register shuffle tree ----
  {
    f32x4 pm[2];
#pragma unroll
    for (int mi = 0; mi < 2; mi++)
#pragma unroll
      for (int r = 0; r < 4; r++) pm[mi][r] = fmaxf(x[0][mi][r], x[1][mi][r]);
#pragma unroll
    for (int d = 1; d < 16; d <<= 1)
#pragma unroll
      for (int mi = 0; mi < 2; mi++)
#pragma unroll
        for (int r = 0; r < 4; r++) pm[mi][r] = fmaxf(pm[mi][r], __shfl_xor(pm[mi][r], d));
    if (lr == 0) {
#pragma unroll
      for (int mi = 0; mi < 2; mi++) {
        int mt = w + mi * 2;
        *(f32x4*)&part[mt * 16 + hi * 4] = pm[mi];
      }
    }
  }
  __syncthreads();

  // ---- output projection: 128 outputs, one per thread (f32) ----
  {
    int o = tid;
    const float* wr = out_w + o * 64;
    float a0 = 0.f, a1 = 0.f, a2 = 0.f, a3 = 0.f;
#pragma unroll
    for (int i = 0; i < 16; i++) {
      float4 wv = *(const float4*)(wr + i * 4);
      float4 pv = *(const float4*)&part[i * 4];
      a0 = fmaf(pv.x, wv.x, a0);
      a1 = fmaf(pv.y, wv.y, a1);
      a2 = fmaf(pv.z, wv.z, a2);
      a3 = fmaf(pv.w, wv.w, a3);
    }
    out[(size_t)m * OUTD + o] = out_b[o] + (a0 + a1) + (a2 + a3);
  }
}

extern "C" void kernel_launch(void* const* d_in, const int* in_sizes, int n_in,
                              void* d_out, int out_size, void* d_ws, size_t ws_size,
                              hipStream_t stream) {
  const float* xyz         = (const float*)d_in[0];
  const float* new_xyz     = (const float*)d_in[1];
  const float* features    = (const float*)d_in[2];
  const int*   group_idx   = (const int*)d_in[3];
  const unsigned char* empty_mask = (const unsigned char*)d_in[4];
  const float* pos_w1      = (const float*)d_in[5];
  const float* pos_bn_g    = (const float*)d_in[6];
  const float* pos_bn_b    = (const float*)d_in[7];
  const float* pos_bn_mean = (const float*)d_in[8];
  const float* pos_bn_var  = (const float*)d_in[9];
  const float* pos_w2      = (const float*)d_in[10];
  const float* pos_b2      = (const float*)d_in[11];
  const float* ln1_g       = (const float*)d_in[12];
  const float* ln1_b       = (const float*)d_in[13];
  const float* qkv_w       = (const float*)d_in[14];
  const float* qkv_b       = (const float*)d_in[15];
  const float* aow         = (const float*)d_in[16];
  const float* aob         = (const float*)d_in[17];
  const float* ln2_g       = (const float*)d_in[18];
  const float* ln2_b       = (const float*)d_in[19];
  const float* f1w         = (const float*)d_in[20];
  const float* f1b         = (const float*)d_in[21];
  const float* f2w         = (const float*)d_in[22];
  const float* f2b         = (const float*)d_in[23];
  const float* out_w       = (const float*)d_in[24];
  const float* out_b       = (const float*)d_in[25];
  float* out = (float*)d_out;
  unsigned char* ws = (unsigned char*)d_ws;

  hipLaunchKernelGGL(convert_weights, dim3(265), dim3(256), 0, stream,
                     qkv_w, aow, f1w, f2w, pos_w2, pos_w1,
                     pos_bn_g, pos_bn_b, pos_bn_mean, pos_bn_var, ws);

  hipLaunchKernelGGL(nvt_mfma, dim3(MQ), dim3(128), 0, stream,
                     xyz, new_xyz, features, group_idx, empty_mask,
                     pos_b2, ln1_g, ln1_b, qkv_b, aob, ln2_g, ln2_b,
                     f1b, f2b, out_w, out_b, ws, out);
}

// Round 16
// 1408.235 us; speedup vs baseline: 1.1523x; 1.1523x over previous
//
#include <hip/hip_runtime.h>
#include <hip/hip_bf16.h>
#include <math.h>

#define MQ   65536
#define OUTD 128

typedef __attribute__((ext_vector_type(8))) short bf16x8;
typedef __attribute__((ext_vector_type(4))) short bf16x4;
typedef __attribute__((ext_vector_type(4))) float f32x4;

// ws byte offsets (bf16 weights + folded pos params)
#define WS_QKV   0        // 2*192*64 bf16 = 49152B
#define WS_AOW   49152    // 2*64*64       = 16384B
#define WS_F1W   65536    // 2*128*64      = 32768B
#define WS_F2W   98304    // 2*64*128      = 32768B
#define WS_PW2   131072   // 64*32         = 4096B
#define WS_W1F   135168   // 32*3 f32      = 384B
#define WS_PBF   135552   // 32 f32        = 128B

__device__ __forceinline__ unsigned short f2bf(float f) {
  unsigned u = __float_as_uint(f);
  u = (u + 0x7FFFu + ((u >> 16) & 1u)) >> 16;   // RTN
  return (unsigned short)u;
}

__device__ __forceinline__ f32x4 mfma16(bf16x8 a, bf16x8 b, f32x4 c) {
  return __builtin_amdgcn_mfma_f32_16x16x32_bf16(a, b, c, 0, 0, 0);
}

__device__ __forceinline__ unsigned pk2(float a, float b) {
  union { __hip_bfloat162 h; unsigned u; } c;
  float2 p; p.x = a; p.y = b;
  c.h = __float22bfloat162_rn(p);
  return c.u;
}

__device__ __forceinline__ bf16x4 pack4(f32x4 v) {
  union { unsigned u[2]; bf16x4 s; } c;
  c.u[0] = pk2(v[0], v[1]);
  c.u[1] = pk2(v[2], v[3]);
  return c.s;
}

__device__ __forceinline__ bf16x8 pack8(const float* v) {
  union { unsigned u[4]; bf16x8 s; } c;
#pragma unroll
  for (int i = 0; i < 4; i++) c.u[i] = pk2(v[2*i], v[2*i+1]);
  return c.s;
}

// Opaque compiler fence: pins LDS reads above / writes below (same-wave WAR in fused stage).
__device__ __forceinline__ void cfence() { asm volatile("" ::: "memory"); }

// ---------------- weight conversion prologue (unchanged, round-2-verified) ----------------
extern "C" __global__ __launch_bounds__(256)
void convert_weights(const float* __restrict__ qkv_w, const float* __restrict__ aow,
                     const float* __restrict__ f1w,  const float* __restrict__ f2w,
                     const float* __restrict__ pw2,  const float* __restrict__ pw1,
                     const float* __restrict__ png,  const float* __restrict__ pnb,
                     const float* __restrict__ pnm,  const float* __restrict__ pnv,
                     unsigned char* __restrict__ ws) {
  int i = blockIdx.x * 256 + threadIdx.x;
  if (i < 24576) {
    ((unsigned short*)(ws + WS_QKV))[i] = f2bf(qkv_w[i]);
  } else if (i < 32768) {
    int j = i - 24576; ((unsigned short*)(ws + WS_AOW))[j] = f2bf(aow[j]);
  } else if (i < 49152) {
    int j = i - 32768; ((unsigned short*)(ws + WS_F1W))[j] = f2bf(f1w[j]);
  } else if (i < 65536) {
    int j = i - 49152; ((unsigned short*)(ws + WS_F2W))[j] = f2bf(f2w[j]);
  } else if (i < 67584) {
    int j = i - 65536; ((unsigned short*)(ws + WS_PW2))[j] = f2bf(pw2[j]);
  } else if (i < 67616) {
    int k = i - 67584;
    float s = png[k] * rsqrtf(pnv[k] + 1e-5f);
    float* w1f = (float*)(ws + WS_W1F);
    float* pbf = (float*)(ws + WS_PBF);
    w1f[k*3+0] = pw1[k*3+0] * s;
    w1f[k*3+1] = pw1[k*3+1] * s;
    w1f[k*3+2] = pw1[k*3+2] * s;
    pbf[k] = pnb[k] - pnm[k] * s;
  }
}

// ---------------- main fused kernel: 1 group / block, 2 waves, residual x in registers ----------------
// x[nt][mi][r] = X[ch = (w+mi*2)*16 + hi*4 + r][tok = nt*16 + lr]
// Session-best structure (round 10, 1408us): fused scores+softmax+PV with in-register
// P redistribution; 7 barriers/layer -> this layout; residual in registers.
extern "C" __global__ __launch_bounds__(128, 2)
void nvt_mfma(const float* __restrict__ xyz,
              const float* __restrict__ new_xyz,
              const float* __restrict__ features,
              const int* __restrict__ group_idx,
              const unsigned char* __restrict__ empty_mask,
              const float* __restrict__ pos_b2,
              const float* __restrict__ ln1_g, const float* __restrict__ ln1_b,
              const float* __restrict__ qkv_b,
              const float* __restrict__ aob,
              const float* __restrict__ ln2_g, const float* __restrict__ ln2_b,
              const float* __restrict__ f1b,
              const float* __restrict__ f2b,
              const float* __restrict__ out_w, const float* __restrict__ out_b,
              const unsigned char* __restrict__ ws,
              float* __restrict__ out) {
  // LDS 18944B:
  //   S  @0     [32][72] bf16 (alias Hs[32][40], part f32[2][64])
  //   Qb @4608  [32][72]      (alias A2; Fb[32][136] spans Qb+Kb)
  //   Kb @9216  [32][72]
  //   Vt @13824 [64][40]      (alias lnbuf f32[2][32][2] in first 512B)
  __shared__ __align__(16) unsigned char smem[18944];
  unsigned short* S  = (unsigned short*)smem;
  unsigned short* Qb = (unsigned short*)(smem + 4608);
  unsigned short* Kb = (unsigned short*)(smem + 9216);
  unsigned short* Fb = (unsigned short*)(smem + 4608);   // stride 136
  unsigned short* Vt = (unsigned short*)(smem + 13824);  // [64][40]
  unsigned short* Hs = S;                                // h staging [32][40]
  float*          part  = (float*)smem;                  // [2][64]
  float*          lnbuf = (float*)(smem + 13824);        // [2][32][2]
  unsigned short* A2 = Qb;

  const unsigned short* qkvw_b = (const unsigned short*)(ws + WS_QKV);
  const unsigned short* aow_b  = (const unsigned short*)(ws + WS_AOW);
  const unsigned short* f1w_b  = (const unsigned short*)(ws + WS_F1W);
  const unsigned short* f2w_b  = (const unsigned short*)(ws + WS_F2W);
  const unsigned short* w2b    = (const unsigned short*)(ws + WS_PW2);
  const float* w1f = (const float*)(ws + WS_W1F);
  const float* pbf = (const float*)(ws + WS_PBF);

  const int m    = blockIdx.x;
  const int tid  = threadIdx.x;
  const int w    = tid >> 6;       // wave 0/1
  const int lane = tid & 63;
  const int lr   = lane & 15;
  const int hi   = lane >> 4;
  const bool empty = empty_mask[m] != 0;

  // ---- stage A: h -> Hs ; gather features into x registers ----
  {
    int t = tid & 31, kb = tid >> 5;
    int idx = group_idx[m * 32 + t];
    float g0 = xyz[idx*3+0] - new_xyz[m*3+0];
    float g1 = xyz[idx*3+1] - new_xyz[m*3+1];
    float g2 = xyz[idx*3+2] - new_xyz[m*3+2];
    if (empty) { g0 = 0.f; g1 = 0.f; g2 = 0.f; }
    float hf[8];
#pragma unroll
    for (int j = 0; j < 8; j++) {
      int k = kb * 8 + j;
      float hp = fmaf(g0, w1f[k*3+0], fmaf(g1, w1f[k*3+1], g2 * w1f[k*3+2])) + pbf[k];
      hf[j] = fmaxf(hp, 0.f);
    }
    *(bf16x8*)&Hs[t * 40 + kb * 8] = pack8(hf);
  }
  f32x4 x[2][2];
  {
    int tg[2];
    tg[0] = group_idx[m * 32 + lr];
    tg[1] = group_idx[m * 32 + 16 + lr];
#pragma unroll
    for (int nt = 0; nt < 2; nt++)
#pragma unroll
      for (int mi = 0; mi < 2; mi++) {
        int mt = w + mi * 2;
        x[nt][mi] = *(const f32x4*)(features + (size_t)tg[nt] * 64 + mt * 16 + hi * 4);
      }
    if (empty) {
#pragma unroll
      for (int nt = 0; nt < 2; nt++)
#pragma unroll
        for (int mi = 0; mi < 2; mi++) { x[nt][mi][0]=0.f; x[nt][mi][1]=0.f; x[nt][mi][2]=0.f; x[nt][mi][3]=0.f; }
    }
  }
  __syncthreads();

  // ---- pos MLP layer 2 via MFMA: x += h @ w2^T + b2 ----
  {
    bf16x8 bh[2];
#pragma unroll
    for (int nt = 0; nt < 2; nt++)
      bh[nt] = *(const bf16x8*)&Hs[(nt * 16 + lr) * 40 + hi * 8];
#pragma unroll
    for (int mi = 0; mi < 2; mi++) {
      int mt = w + mi * 2;
      bf16x8 a = *(const bf16x8*)(w2b + (mt * 16 + lr) * 32 + hi * 8);
      float4 b4 = *(const float4*)(pos_b2 + mt * 16 + hi * 4);
      f32x4 bias; bias[0] = b4.x; bias[1] = b4.y; bias[2] = b4.z; bias[3] = b4.w;
#pragma unroll
      for (int nt = 0; nt < 2; nt++) x[nt][mi] += mfma16(a, bh[nt], bias);
    }
  }
  // (no barrier here: LN's publish barrier below provides the WAR protection)

  // LN: x regs -> S (bf16), cross-wave partial-sum exchange through lnbuf
  auto LN = [&](const float* g, const float* b) {
    float s[2], s2[2];
#pragma unroll
    for (int nt = 0; nt < 2; nt++) {
      float a = 0.f, a2 = 0.f;
#pragma unroll
      for (int mi = 0; mi < 2; mi++)
#pragma unroll
        for (int r = 0; r < 4; r++) { float v = x[nt][mi][r]; a += v; a2 = fmaf(v, v, a2); }
      a  += __shfl_xor(a, 16);  a  += __shfl_xor(a, 32);
      a2 += __shfl_xor(a2, 16); a2 += __shfl_xor(a2, 32);
      s[nt] = a; s2[nt] = a2;
    }
    if (hi == 0) {
#pragma unroll
      for (int nt = 0; nt < 2; nt++) {
        int tok = nt * 16 + lr;
        lnbuf[w * 64 + tok * 2 + 0] = s[nt];
        lnbuf[w * 64 + tok * 2 + 1] = s2[nt];
      }
    }
    __syncthreads();
#pragma unroll
    for (int nt = 0; nt < 2; nt++) {
      int tok = nt * 16 + lr;
      float st  = s[nt]  + lnbuf[(1 - w) * 64 + tok * 2 + 0];
      float s2t = s2[nt] + lnbuf[(1 - w) * 64 + tok * 2 + 1];
      float mu  = st * (1.f/64.f);
      float var = s2t * (1.f/64.f) - mu * mu;
      float inv = rsqrtf(fmaxf(var, 0.f) + 1e-5f);
#pragma unroll
      for (int mi = 0; mi < 2; mi++) {
        int mt = w + mi * 2;
        float4 g4 = *(const float4*)(g + mt * 16 + hi * 4);
        float4 b4 = *(const float4*)(b + mt * 16 + hi * 4);
        f32x4 o;
        o[0] = fmaf((x[nt][mi][0] - mu) * inv, g4.x, b4.x);
        o[1] = fmaf((x[nt][mi][1] - mu) * inv, g4.y, b4.y);
        o[2] = fmaf((x[nt][mi][2] - mu) * inv, g4.z, b4.z);
        o[3] = fmaf((x[nt][mi][3] - mu) * inv, g4.w, b4.w);
        *(bf16x4*)&S[tok * 72 + mt * 16 + hi * 4] = pack4(o);
      }
    }
    __syncthreads();
  };

  // ---- transformer layers ----
  for (int ly = 0; ly < 2; ly++) {
    LN(ln1_g + ly*64, ln1_b + ly*64);

    // qkv: Q,K as D[o][t] (A=W rows); V swapped as D[t][o] (A=S rows) -> packed Vt store
    {
      bf16x8 bs[2][2];
#pragma unroll
      for (int nt = 0; nt < 2; nt++)
#pragma unroll
        for (int kt = 0; kt < 2; kt++)
          bs[nt][kt] = *(const bf16x8*)&S[(nt * 16 + lr) * 72 + kt * 32 + hi * 8];
      const unsigned short* Wq = qkvw_b + ly * 192 * 64;
      const float* Bq = qkv_b + ly * 192;
#pragma unroll
      for (int mi = 0; mi < 4; mi++) {
        int mt = w + mi * 2;
        bf16x8 a[2];
#pragma unroll
        for (int kt = 0; kt < 2; kt++)
          a[kt] = *(const bf16x8*)(Wq + (mt * 16 + lr) * 64 + kt * 32 + hi * 8);
        float4 b4 = *(const float4*)(Bq + mt * 16 + hi * 4);
#pragma unroll
        for (int nt = 0; nt < 2; nt++) {
          f32x4 acc; acc[0] = b4.x; acc[1] = b4.y; acc[2] = b4.z; acc[3] = b4.w;
#pragma unroll
          for (int kt = 0; kt < 2; kt++) acc = mfma16(a[kt], bs[nt][kt], acc);
          int t = nt * 16 + lr;
          unsigned short* dst = (mt < 4) ? Qb : Kb;
          *(bf16x4*)&dst[t * 72 + (mt & 3) * 16 + hi * 4] = pack4(acc);
        }
      }
      // V swapped: acc[r] = V[tok=nt*16+hi*4+r][ch=mtv*16+lr]
#pragma unroll
      for (int mvi = 0; mvi < 2; mvi++) {
        int mtv = w + mvi * 2;
        bf16x8 b0 = *(const bf16x8*)(Wq + (128 + mtv * 16 + lr) * 64 + hi * 8);
        bf16x8 b1 = *(const bf16x8*)(Wq + (128 + mtv * 16 + lr) * 64 + 32 + hi * 8);
        float bv = Bq[128 + mtv * 16 + lr];
#pragma unroll
        for (int nt = 0; nt < 2; nt++) {
          f32x4 acc; acc[0] = bv; acc[1] = bv; acc[2] = bv; acc[3] = bv;
          acc = mfma16(bs[nt][0], b0, acc);
          acc = mfma16(bs[nt][1], b1, acc);
          *(bf16x4*)&Vt[(mtv * 16 + lr) * 40 + nt * 16 + hi * 4] = pack4(acc);
        }
      }
    }
    __syncthreads();

    // ---- fused scores + softmax + PV (wave-local; own i-tile = own token-tile w) ----
    {
      bf16x8 ak[2][2], bq[2], av[4];
#pragma unroll
      for (int jt = 0; jt < 2; jt++)
#pragma unroll
        for (int kt = 0; kt < 2; kt++)
          ak[jt][kt] = *(const bf16x8*)&Kb[(jt * 16 + lr) * 72 + kt * 32 + hi * 8];
#pragma unroll
      for (int kt = 0; kt < 2; kt++)
        bq[kt] = *(const bf16x8*)&Qb[(w * 16 + lr) * 72 + kt * 32 + hi * 8];
#pragma unroll
      for (int mt = 0; mt < 4; mt++)
        av[mt] = *(const bf16x8*)&Vt[(mt * 16 + lr) * 40 + hi * 8];
      cfence();   // pin reads above before A2 writes below (own-row WAR; LDS in-order per wave)

      // scores: p[jt][r] = P[j=jt*16+hi*4+r][i=w*16+lr]
      f32x4 p[2];
#pragma unroll
      for (int jt = 0; jt < 2; jt++) {
        f32x4 acc; acc[0] = 0.f; acc[1] = 0.f; acc[2] = 0.f; acc[3] = 0.f;
#pragma unroll
        for (int kt = 0; kt < 2; kt++) acc = mfma16(ak[jt][kt], bq[kt], acc);
        p[jt] = acc;
      }
      float mx = -3.4e38f;
#pragma unroll
      for (int jt = 0; jt < 2; jt++)
#pragma unroll
        for (int r = 0; r < 4; r++) { p[jt][r] *= 0.125f; mx = fmaxf(mx, p[jt][r]); }
      mx = fmaxf(mx, __shfl_xor(mx, 16));
      mx = fmaxf(mx, __shfl_xor(mx, 32));
      float sum = 0.f;
#pragma unroll
      for (int jt = 0; jt < 2; jt++)
#pragma unroll
        for (int r = 0; r < 4; r++) { float e = __expf(p[jt][r] - mx); p[jt][r] = e; sum += e; }
      sum += __shfl_xor(sum, 16);
      sum += __shfl_xor(sum, 32);
      float inv = 1.f / sum;

      // pack P (bf16) and redistribute to PV B-fragment layout via 8 shuffles:
      // target lane (lr,hi) needs P[j=hi*8+jj][i=w*16+lr]; source jt=hi>>1, hi'=2(hi&1)+(jj>>2).
      unsigned u[2][2];
#pragma unroll
      for (int jt = 0; jt < 2; jt++) {
        u[jt][0] = pk2(p[jt][0] * inv, p[jt][1] * inv);
        u[jt][1] = pk2(p[jt][2] * inv, p[jt][3] * inv);
      }
      int s1 = lr + 32 * (hi & 1);   // lane (lr, hi'=2*(hi&1))
      int s2 = s1 + 16;              // lane (lr, hi'+1)
      unsigned c0 = __shfl(u[0][0], s1), c1 = __shfl(u[0][1], s1);
      unsigned d0 = __shfl(u[0][0], s2), d1 = __shfl(u[0][1], s2);
      unsigned e0 = __shfl(u[1][0], s1), e1 = __shfl(u[1][1], s1);
      unsigned f0 = __shfl(u[1][0], s2), f1 = __shfl(u[1][1], s2);
      bool sel = (hi >> 1) != 0;
      union { unsigned uu[4]; bf16x8 v; } bp;
      bp.uu[0] = sel ? e0 : c0;
      bp.uu[1] = sel ? e1 : c1;
      bp.uu[2] = sel ? f0 : d0;
      bp.uu[3] = sel ? f1 : d1;

      // PV: D[ch][tok own tile] = mfma(Vt rows, bp) -> A2[tok][ch], rows w*16+lr (wave-disjoint)
#pragma unroll
      for (int mt = 0; mt < 4; mt++) {
        f32x4 acc; acc[0] = 0.f; acc[1] = 0.f; acc[2] = 0.f; acc[3] = 0.f;
        acc = mfma16(av[mt], bp.v, acc);
        *(bf16x4*)&A2[(w * 16 + lr) * 72 + mt * 16 + hi * 4] = pack4(acc);
      }
    }
    __syncthreads();

    // attn_out: x += A2 @ Wao^T + b (accumulate in registers)
    {
      bf16x8 ba[2][2];
#pragma unroll
      for (int nt = 0; nt < 2; nt++)
#pragma unroll
        for (int kt = 0; kt < 2; kt++)
          ba[nt][kt] = *(const bf16x8*)&A2[(nt * 16 + lr) * 72 + kt * 32 + hi * 8];
      const unsigned short* Wo = aow_b + ly * 64 * 64;
      const float* Bo = aob + ly * 64;
#pragma unroll
      for (int mi = 0; mi < 2; mi++) {
        int mt = w + mi * 2;
        bf16x8 a[2];
#pragma unroll
        for (int kt = 0; kt < 2; kt++)
          a[kt] = *(const bf16x8*)(Wo + (mt * 16 + lr) * 64 + kt * 32 + hi * 8);
        float4 b4 = *(const float4*)(Bo + mt * 16 + hi * 4);
#pragma unroll
        for (int nt = 0; nt < 2; nt++) {
          f32x4 acc; acc[0] = b4.x; acc[1] = b4.y; acc[2] = b4.z; acc[3] = b4.w;
#pragma unroll
          for (int kt = 0; kt < 2; kt++) acc = mfma16(a[kt], ba[nt][kt], acc);
          x[nt][mi] += acc;
        }
      }
    }
    // (no barrier: LN2's publish barrier protects A2 reads; next Qb writer is ff1 after LN2b)

    LN(ln2_g + ly*64, ln2_b + ly*64);

    // ff1: F[t][o] = relu(S @ W1^T + b1), o<128
    {
      bf16x8 bs[2][2];
#pragma unroll
      for (int nt = 0; nt < 2; nt++)
#pragma unroll
        for (int kt = 0; kt < 2; kt++)
          bs[nt][kt] = *(const bf16x8*)&S[(nt * 16 + lr) * 72 + kt * 32 + hi * 8];
      const unsigned short* W1 = f1w_b + ly * 128 * 64;
      const float* B1 = f1b + ly * 128;
#pragma unroll
      for (int mi = 0; mi < 4; mi++) {
        int mt = w + mi * 2;
        bf16x8 a[2];
#pragma unroll
        for (int kt = 0; kt < 2; kt++)
          a[kt] = *(const bf16x8*)(W1 + (mt * 16 + lr) * 64 + kt * 32 + hi * 8);
        float4 b4 = *(const float4*)(B1 + mt * 16 + hi * 4);
#pragma unroll
        for (int nt = 0; nt < 2; nt++) {
          f32x4 acc; acc[0] = b4.x; acc[1] = b4.y; acc[2] = b4.z; acc[3] = b4.w;
#pragma unroll
          for (int kt = 0; kt < 2; kt++) acc = mfma16(a[kt], bs[nt][kt], acc);
#pragma unroll
          for (int r = 0; r < 4; r++) acc[r] = fmaxf(acc[r], 0.f);
          *(bf16x4*)&Fb[(nt * 16 + lr) * 136 + mt * 16 + hi * 4] = pack4(acc);
        }
      }
    }
    __syncthreads();

    // ff2: x += F @ W2^T + b2 (accumulate in registers)
    {
      bf16x8 bfr[2][4];
#pragma unroll
      for (int nt = 0; nt < 2; nt++)
#pragma unroll
        for (int kt = 0; kt < 4; kt++)
          bfr[nt][kt] = *(const bf16x8*)&Fb[(nt * 16 + lr) * 136 + kt * 32 + hi * 8];
      const unsigned short* W2 = f2w_b + ly * 64 * 128;
      const float* B2 = f2b + ly * 64;
#pragma unroll
      for (int mi = 0; mi < 2; mi++) {
        int mt = w + mi * 2;
        bf16x8 a[4];
#pragma unroll
        for (int kt = 0; kt < 4; kt++)
          a[kt] = *(const bf16x8*)(W2 + (mt * 16 + lr) * 128 + kt * 32 + hi * 8);
        float4 b4 = *(const float4*)(B2 + mt * 16 + hi * 4);
#pragma unroll
        for (int nt = 0; nt < 2; nt++) {
          f32x4 acc; acc[0] = b4.x; acc[1] = b4.y; acc[2] = b4.z; acc[3] = b4.w;
#pragma unroll
          for (int kt = 0; kt < 4; kt++) acc = mfma16(a[kt], bfr[nt][kt], acc);
          x[nt][mi] += acc;
        }
      }
    }
    // (no barrier: next LN1's publish barrier protects F reads; after last layer only reg ops)
  }

  // ---- max pool over tokens: register shuffle tree ----
  {
    f32x4 pm[2];
#pragma unroll
    for (int mi = 0; mi < 2; mi++)
#pragma unroll
      for (int r = 0; r < 4; r++) pm[mi][r] = fmaxf(x[0][mi][r], x[1][mi][r]);
#pragma unroll
    for (int d = 1; d < 16; d <<= 1)
#pragma unroll
      for (int mi = 0; mi < 2; mi++)
#pragma unroll
        for (int r = 0; r < 4; r++) pm[mi][r] = fmaxf(pm[mi][r], __shfl_xor(pm[mi][r], d));
    if (lr == 0) {
#pragma unroll
      for (int mi = 0; mi < 2; mi++) {
        int mt = w + mi * 2;
        *(f32x4*)&part[mt * 16 + hi * 4] = pm[mi];
      }
    }
  }
  __syncthreads();

  // ---- output projection: 128 outputs, one per thread (f32) ----
  {
    int o = tid;
    const float* wr = out_w + o * 64;
    float a0 = 0.f, a1 = 0.f, a2 = 0.f, a3 = 0.f;
#pragma unroll
    for (int i = 0; i < 16; i++) {
      float4 wv = *(const float4*)(wr + i * 4);
      float4 pv = *(const float4*)&part[i * 4];
      a0 = fmaf(pv.x, wv.x, a0);
      a1 = fmaf(pv.y, wv.y, a1);
      a2 = fmaf(pv.z, wv.z, a2);
      a3 = fmaf(pv.w, wv.w, a3);
    }
    out[(size_t)m * OUTD + o] = out_b[o] + (a0 + a1) + (a2 + a3);
  }
}

extern "C" void kernel_launch(void* const* d_in, const int* in_sizes, int n_in,
                              void* d_out, int out_size, void* d_ws, size_t ws_size,
                              hipStream_t stream) {
  const float* xyz         = (const float*)d_in[0];
  const float* new_xyz     = (const float*)d_in[1];
  const float* features    = (const float*)d_in[2];
  const int*   group_idx   = (const int*)d_in[3];
  const unsigned char* empty_mask = (const unsigned char*)d_in[4];
  const float* pos_w1      = (const float*)d_in[5];
  const float* pos_bn_g    = (const float*)d_in[6];
  const float* pos_bn_b    = (const float*)d_in[7];
  const float* pos_bn_mean = (const float*)d_in[8];
  const float* pos_bn_var  = (const float*)d_in[9];
  const float* pos_w2      = (const float*)d_in[10];
  const float* pos_b2      = (const float*)d_in[11];
  const float* ln1_g       = (const float*)d_in[12];
  const float* ln1_b       = (const float*)d_in[13];
  const float* qkv_w       = (const float*)d_in[14];
  const float* qkv_b       = (const float*)d_in[15];
  const float* aow         = (const float*)d_in[16];
  const float* aob         = (const float*)d_in[17];
  const float* ln2_g       = (const float*)d_in[18];
  const float* ln2_b       = (const float*)d_in[19];
  const float* f1w         = (const float*)d_in[20];
  const float* f1b         = (const float*)d_in[21];
  const float* f2w         = (const float*)d_in[22];
  const float* f2b         = (const float*)d_in[23];
  const float* out_w       = (const float*)d_in[24];
  const float* out_b       = (const float*)d_in[25];
  float* out = (float*)d_out;
  unsigned char* ws = (unsigned char*)d_ws;

  hipLaunchKernelGGL(convert_weights, dim3(265), dim3(256), 0, stream,
                     qkv_w, aow, f1w, f2w, pos_w2, pos_w1,
                     pos_bn_g, pos_bn_b, pos_bn_mean, pos_bn_var, ws);

  hipLaunchKernelGGL(nvt_mfma, dim3(MQ), dim3(128), 0, stream,
                     xyz, new_xyz, features, group_idx, empty_mask,
                     pos_b2, ln1_g, ln1_b, qkv_b, aob, ln2_g, ln2_b,
                     f1b, f2b, out_w, out_b, ws, out);
}

// Round 17
// 943.120 us; speedup vs baseline: 1.7205x; 1.4932x over previous
//
#include <hip/hip_runtime.h>
#include <hip/hip_bf16.h>
#include <math.h>

#define MQ   65536
#define OUTD 128
#define ARB  18944   // per-group LDS arena bytes

typedef __attribute__((ext_vector_type(8))) short bf16x8;
typedef __attribute__((ext_vector_type(4))) short bf16x4;
typedef __attribute__((ext_vector_type(4))) float f32x4;

// ws byte offsets (bf16 weights + folded pos params)
#define WS_QKV   0
#define WS_AOW   49152
#define WS_F1W   65536
#define WS_F2W   98304
#define WS_PW2   131072
#define WS_W1F   135168
#define WS_PBF   135552

__device__ __forceinline__ unsigned short f2bf(float f) {
  unsigned u = __float_as_uint(f);
  u = (u + 0x7FFFu + ((u >> 16) & 1u)) >> 16;   // RTN
  return (unsigned short)u;
}

__device__ __forceinline__ f32x4 mfma16(bf16x8 a, bf16x8 b, f32x4 c) {
  return __builtin_amdgcn_mfma_f32_16x16x32_bf16(a, b, c, 0, 0, 0);
}

__device__ __forceinline__ unsigned pk2(float a, float b) {
  union { __hip_bfloat162 h; unsigned u; } c;
  float2 p; p.x = a; p.y = b;
  c.h = __float22bfloat162_rn(p);
  return c.u;
}

__device__ __forceinline__ bf16x4 pack4(f32x4 v) {
  union { unsigned u[2]; bf16x4 s; } c;
  c.u[0] = pk2(v[0], v[1]);
  c.u[1] = pk2(v[2], v[3]);
  return c.s;
}

__device__ __forceinline__ bf16x8 pack8(const float* v) {
  union { unsigned u[4]; bf16x8 s; } c;
#pragma unroll
  for (int i = 0; i < 4; i++) c.u[i] = pk2(v[2*i], v[2*i+1]);
  return c.s;
}

__device__ __forceinline__ void cfence() { asm volatile("" ::: "memory"); }

// ---------------- weight conversion prologue (unchanged, round-2-verified) ----------------
extern "C" __global__ __launch_bounds__(256)
void convert_weights(const float* __restrict__ qkv_w, const float* __restrict__ aow,
                     const float* __restrict__ f1w,  const float* __restrict__ f2w,
                     const float* __restrict__ pw2,  const float* __restrict__ pw1,
                     const float* __restrict__ png,  const float* __restrict__ pnb,
                     const float* __restrict__ pnm,  const float* __restrict__ pnv,
                     unsigned char* __restrict__ ws) {
  int i = blockIdx.x * 256 + threadIdx.x;
  if (i < 24576) {
    ((unsigned short*)(ws + WS_QKV))[i] = f2bf(qkv_w[i]);
  } else if (i < 32768) {
    int j = i - 24576; ((unsigned short*)(ws + WS_AOW))[j] = f2bf(aow[j]);
  } else if (i < 49152) {
    int j = i - 32768; ((unsigned short*)(ws + WS_F1W))[j] = f2bf(f1w[j]);
  } else if (i < 65536) {
    int j = i - 49152; ((unsigned short*)(ws + WS_F2W))[j] = f2bf(f2w[j]);
  } else if (i < 67584) {
    int j = i - 65536; ((unsigned short*)(ws + WS_PW2))[j] = f2bf(pw2[j]);
  } else if (i < 67616) {
    int k = i - 67584;
    float s = png[k] * rsqrtf(pnv[k] + 1e-5f);
    float* w1f = (float*)(ws + WS_W1F);
    float* pbf = (float*)(ws + WS_PBF);
    w1f[k*3+0] = pw1[k*3+0] * s;
    w1f[k*3+1] = pw1[k*3+1] * s;
    w1f[k*3+2] = pw1[k*3+2] * s;
    pbf[k] = pnb[k] - pnm[k] * s;
  }
}

// ---------------- main fused kernel: TWO groups / block, 2 waves ----------------
// Round-10 structure per group; weight fragments loaded ONCE per block and used by
// both groups' MFMAs (2x MFMA:load ratio); 7 barriers/layer now cover 2 groups.
// x[G][nt][mi][r] = X_G[ch=(w+mi*2)*16+hi*4+r][tok=nt*16+lr]
extern "C" __global__ __launch_bounds__(128, 2)
void nvt_mfma(const float* __restrict__ xyz,
              const float* __restrict__ new_xyz,
              const float* __restrict__ features,
              const int* __restrict__ group_idx,
              const unsigned char* __restrict__ empty_mask,
              const float* __restrict__ pos_b2,
              const float* __restrict__ ln1_g, const float* __restrict__ ln1_b,
              const float* __restrict__ qkv_b,
              const float* __restrict__ aob,
              const float* __restrict__ ln2_g, const float* __restrict__ ln2_b,
              const float* __restrict__ f1b,
              const float* __restrict__ f2b,
              const float* __restrict__ out_w, const float* __restrict__ out_b,
              const unsigned char* __restrict__ ws,
              float* __restrict__ out) {
  // Two arenas, each the round-10 layout:
  //   S @0 [32][72] (alias Hs[32][40], part f32[2][64]) | Qb @4608 (alias A2; Fb spans Qb+Kb)
  //   Kb @9216 | Vt @13824 [64][40] (alias lnbuf f32[2][32][2])
  __shared__ __align__(16) unsigned char smem[2 * ARB];
  unsigned short *S[2], *Qb[2], *Kb[2], *Fb[2], *Vt[2], *Hs[2], *A2[2];
  float *part[2], *lnbuf[2];
#pragma unroll
  for (int G = 0; G < 2; G++) {
    unsigned char* a = smem + G * ARB;
    S[G]  = (unsigned short*)a;
    Qb[G] = (unsigned short*)(a + 4608);
    Kb[G] = (unsigned short*)(a + 9216);
    Fb[G] = (unsigned short*)(a + 4608);
    Vt[G] = (unsigned short*)(a + 13824);
    Hs[G] = S[G];
    A2[G] = Qb[G];
    part[G]  = (float*)a;
    lnbuf[G] = (float*)(a + 13824);
  }

  const unsigned short* qkvw_b = (const unsigned short*)(ws + WS_QKV);
  const unsigned short* aow_b  = (const unsigned short*)(ws + WS_AOW);
  const unsigned short* f1w_b  = (const unsigned short*)(ws + WS_F1W);
  const unsigned short* f2w_b  = (const unsigned short*)(ws + WS_F2W);
  const unsigned short* w2b    = (const unsigned short*)(ws + WS_PW2);
  const float* w1f = (const float*)(ws + WS_W1F);
  const float* pbf = (const float*)(ws + WS_PBF);

  const int tid  = threadIdx.x;
  const int w    = tid >> 6;
  const int lane = tid & 63;
  const int lr   = lane & 15;
  const int hi   = lane >> 4;
  int mg[2];
  mg[0] = blockIdx.x * 2;
  mg[1] = blockIdx.x * 2 + 1;
  bool empty[2];
  empty[0] = empty_mask[mg[0]] != 0;
  empty[1] = empty_mask[mg[1]] != 0;

  // ---- stage A: h -> Hs[G] ; gather features into x[G] registers ----
#pragma unroll
  for (int G = 0; G < 2; G++) {
    int t = tid & 31, kb = tid >> 5;
    int idx = group_idx[mg[G] * 32 + t];
    float g0 = xyz[idx*3+0] - new_xyz[mg[G]*3+0];
    float g1 = xyz[idx*3+1] - new_xyz[mg[G]*3+1];
    float g2 = xyz[idx*3+2] - new_xyz[mg[G]*3+2];
    if (empty[G]) { g0 = 0.f; g1 = 0.f; g2 = 0.f; }
    float hf[8];
#pragma unroll
    for (int j = 0; j < 8; j++) {
      int k = kb * 8 + j;
      float hp = fmaf(g0, w1f[k*3+0], fmaf(g1, w1f[k*3+1], g2 * w1f[k*3+2])) + pbf[k];
      hf[j] = fmaxf(hp, 0.f);
    }
    *(bf16x8*)&Hs[G][t * 40 + kb * 8] = pack8(hf);
  }
  f32x4 x[2][2][2];
#pragma unroll
  for (int G = 0; G < 2; G++) {
    int tg0 = group_idx[mg[G] * 32 + lr];
    int tg1 = group_idx[mg[G] * 32 + 16 + lr];
#pragma unroll
    for (int mi = 0; mi < 2; mi++) {
      int mt = w + mi * 2;
      x[G][0][mi] = *(const f32x4*)(features + (size_t)tg0 * 64 + mt * 16 + hi * 4);
      x[G][1][mi] = *(const f32x4*)(features + (size_t)tg1 * 64 + mt * 16 + hi * 4);
    }
    if (empty[G]) {
#pragma unroll
      for (int nt = 0; nt < 2; nt++)
#pragma unroll
        for (int mi = 0; mi < 2; mi++) { x[G][nt][mi][0]=0.f; x[G][nt][mi][1]=0.f; x[G][nt][mi][2]=0.f; x[G][nt][mi][3]=0.f; }
    }
  }
  __syncthreads();

  // ---- pos MLP layer 2: x += h @ w2^T + b2 (weights shared across groups) ----
  {
    bf16x8 bh[2][2];
#pragma unroll
    for (int G = 0; G < 2; G++)
#pragma unroll
      for (int nt = 0; nt < 2; nt++)
        bh[G][nt] = *(const bf16x8*)&Hs[G][(nt * 16 + lr) * 40 + hi * 8];
#pragma unroll
    for (int mi = 0; mi < 2; mi++) {
      int mt = w + mi * 2;
      bf16x8 a = *(const bf16x8*)(w2b + (mt * 16 + lr) * 32 + hi * 8);
      float4 b4 = *(const float4*)(pos_b2 + mt * 16 + hi * 4);
      f32x4 bias; bias[0] = b4.x; bias[1] = b4.y; bias[2] = b4.z; bias[3] = b4.w;
#pragma unroll
      for (int G = 0; G < 2; G++)
#pragma unroll
        for (int nt = 0; nt < 2; nt++) x[G][nt][mi] += mfma16(a, bh[G][nt], bias);
    }
  }

  // LN both groups: x regs -> S[G]; one shared barrier pair
  auto LN = [&](const float* g, const float* b) {
    float s[2][2], s2[2][2];
#pragma unroll
    for (int G = 0; G < 2; G++)
#pragma unroll
      for (int nt = 0; nt < 2; nt++) {
        float a = 0.f, a2 = 0.f;
#pragma unroll
        for (int mi = 0; mi < 2; mi++)
#pragma unroll
          for (int r = 0; r < 4; r++) { float v = x[G][nt][mi][r]; a += v; a2 = fmaf(v, v, a2); }
        a  += __shfl_xor(a, 16);  a  += __shfl_xor(a, 32);
        a2 += __shfl_xor(a2, 16); a2 += __shfl_xor(a2, 32);
        s[G][nt] = a; s2[G][nt] = a2;
      }
    if (hi == 0) {
#pragma unroll
      for (int G = 0; G < 2; G++)
#pragma unroll
        for (int nt = 0; nt < 2; nt++) {
          int tok = nt * 16 + lr;
          lnbuf[G][w * 64 + tok * 2 + 0] = s[G][nt];
          lnbuf[G][w * 64 + tok * 2 + 1] = s2[G][nt];
        }
    }
    __syncthreads();
#pragma unroll
    for (int G = 0; G < 2; G++)
#pragma unroll
      for (int nt = 0; nt < 2; nt++) {
        int tok = nt * 16 + lr;
        float st  = s[G][nt]  + lnbuf[G][(1 - w) * 64 + tok * 2 + 0];
        float s2t = s2[G][nt] + lnbuf[G][(1 - w) * 64 + tok * 2 + 1];
        float mu  = st * (1.f/64.f);
        float var = s2t * (1.f/64.f) - mu * mu;
        float inv = rsqrtf(fmaxf(var, 0.f) + 1e-5f);
#pragma unroll
        for (int mi = 0; mi < 2; mi++) {
          int mt = w + mi * 2;
          float4 g4 = *(const float4*)(g + mt * 16 + hi * 4);
          float4 b4 = *(const float4*)(b + mt * 16 + hi * 4);
          f32x4 o;
          o[0] = fmaf((x[G][nt][mi][0] - mu) * inv, g4.x, b4.x);
          o[1] = fmaf((x[G][nt][mi][1] - mu) * inv, g4.y, b4.y);
          o[2] = fmaf((x[G][nt][mi][2] - mu) * inv, g4.z, b4.z);
          o[3] = fmaf((x[G][nt][mi][3] - mu) * inv, g4.w, b4.w);
          *(bf16x4*)&S[G][tok * 72 + mt * 16 + hi * 4] = pack4(o);
        }
      }
    __syncthreads();
  };

  // ---- transformer layers ----
  for (int ly = 0; ly < 2; ly++) {
    LN(ln1_g + ly*64, ln1_b + ly*64);

    // qkv: weight fragments loaded once, MFMA'd for both groups
    {
      bf16x8 bs[2][2][2];
#pragma unroll
      for (int G = 0; G < 2; G++)
#pragma unroll
        for (int nt = 0; nt < 2; nt++)
#pragma unroll
          for (int kt = 0; kt < 2; kt++)
            bs[G][nt][kt] = *(const bf16x8*)&S[G][(nt * 16 + lr) * 72 + kt * 32 + hi * 8];
      const unsigned short* Wq = qkvw_b + ly * 192 * 64;
      const float* Bq = qkv_b + ly * 192;
#pragma unroll
      for (int mi = 0; mi < 4; mi++) {
        int mt = w + mi * 2;
        bf16x8 a0 = *(const bf16x8*)(Wq + (mt * 16 + lr) * 64 + hi * 8);
        bf16x8 a1 = *(const bf16x8*)(Wq + (mt * 16 + lr) * 64 + 32 + hi * 8);
        float4 b4 = *(const float4*)(Bq + mt * 16 + hi * 4);
#pragma unroll
        for (int G = 0; G < 2; G++)
#pragma unroll
          for (int nt = 0; nt < 2; nt++) {
            f32x4 acc; acc[0] = b4.x; acc[1] = b4.y; acc[2] = b4.z; acc[3] = b4.w;
            acc = mfma16(a0, bs[G][nt][0], acc);
            acc = mfma16(a1, bs[G][nt][1], acc);
            int t = nt * 16 + lr;
            unsigned short* dst = (mt < 4) ? Qb[G] : Kb[G];
            *(bf16x4*)&dst[t * 72 + (mt & 3) * 16 + hi * 4] = pack4(acc);
          }
      }
      // V swapped: acc[r] = V[tok=nt*16+hi*4+r][ch=mtv*16+lr]; Wv fragments shared
#pragma unroll
      for (int mvi = 0; mvi < 2; mvi++) {
        int mtv = w + mvi * 2;
        bf16x8 b0 = *(const bf16x8*)(Wq + (128 + mtv * 16 + lr) * 64 + hi * 8);
        bf16x8 b1 = *(const bf16x8*)(Wq + (128 + mtv * 16 + lr) * 64 + 32 + hi * 8);
        float bv = Bq[128 + mtv * 16 + lr];
#pragma unroll
        for (int G = 0; G < 2; G++)
#pragma unroll
          for (int nt = 0; nt < 2; nt++) {
            f32x4 acc; acc[0] = bv; acc[1] = bv; acc[2] = bv; acc[3] = bv;
            acc = mfma16(bs[G][nt][0], b0, acc);
            acc = mfma16(bs[G][nt][1], b1, acc);
            *(bf16x4*)&Vt[G][(mtv * 16 + lr) * 40 + nt * 16 + hi * 4] = pack4(acc);
          }
      }
    }
    __syncthreads();

    // ---- fused scores + softmax + PV, both groups ----
    {
      bf16x8 ak[2][2][2], bq[2][2], av[2][4];
#pragma unroll
      for (int G = 0; G < 2; G++) {
#pragma unroll
        for (int jt = 0; jt < 2; jt++)
#pragma unroll
          for (int kt = 0; kt < 2; kt++)
            ak[G][jt][kt] = *(const bf16x8*)&Kb[G][(jt * 16 + lr) * 72 + kt * 32 + hi * 8];
#pragma unroll
        for (int kt = 0; kt < 2; kt++)
          bq[G][kt] = *(const bf16x8*)&Qb[G][(w * 16 + lr) * 72 + kt * 32 + hi * 8];
#pragma unroll
        for (int mt = 0; mt < 4; mt++)
          av[G][mt] = *(const bf16x8*)&Vt[G][(mt * 16 + lr) * 40 + hi * 8];
      }
      cfence();   // pin reads above before A2 writes below

#pragma unroll
      for (int G = 0; G < 2; G++) {
        f32x4 p[2];
#pragma unroll
        for (int jt = 0; jt < 2; jt++) {
          f32x4 acc; acc[0] = 0.f; acc[1] = 0.f; acc[2] = 0.f; acc[3] = 0.f;
#pragma unroll
          for (int kt = 0; kt < 2; kt++) acc = mfma16(ak[G][jt][kt], bq[G][kt], acc);
          p[jt] = acc;
        }
        float mx = -3.4e38f;
#pragma unroll
        for (int jt = 0; jt < 2; jt++)
#pragma unroll
          for (int r = 0; r < 4; r++) { p[jt][r] *= 0.125f; mx = fmaxf(mx, p[jt][r]); }
        mx = fmaxf(mx, __shfl_xor(mx, 16));
        mx = fmaxf(mx, __shfl_xor(mx, 32));
        float sum = 0.f;
#pragma unroll
        for (int jt = 0; jt < 2; jt++)
#pragma unroll
          for (int r = 0; r < 4; r++) { float e = __expf(p[jt][r] - mx); p[jt][r] = e; sum += e; }
        sum += __shfl_xor(sum, 16);
        sum += __shfl_xor(sum, 32);
        float inv = 1.f / sum;

        unsigned u[2][2];
#pragma unroll
        for (int jt = 0; jt < 2; jt++) {
          u[jt][0] = pk2(p[jt][0] * inv, p[jt][1] * inv);
          u[jt][1] = pk2(p[jt][2] * inv, p[jt][3] * inv);
        }
        int s1 = lr + 32 * (hi & 1);
        int s2 = s1 + 16;
        unsigned c0 = __shfl(u[0][0], s1), c1 = __shfl(u[0][1], s1);
        unsigned d0 = __shfl(u[0][0], s2), d1 = __shfl(u[0][1], s2);
        unsigned e0 = __shfl(u[1][0], s1), e1 = __shfl(u[1][1], s1);
        unsigned f0 = __shfl(u[1][0], s2), f1 = __shfl(u[1][1], s2);
        bool sel = (hi >> 1) != 0;
        union { unsigned uu[4]; bf16x8 v; } bp;
        bp.uu[0] = sel ? e0 : c0;
        bp.uu[1] = sel ? e1 : c1;
        bp.uu[2] = sel ? f0 : d0;
        bp.uu[3] = sel ? f1 : d1;

#pragma unroll
        for (int mt = 0; mt < 4; mt++) {
          f32x4 acc; acc[0] = 0.f; acc[1] = 0.f; acc[2] = 0.f; acc[3] = 0.f;
          acc = mfma16(av[G][mt], bp.v, acc);
          *(bf16x4*)&A2[G][(w * 16 + lr) * 72 + mt * 16 + hi * 4] = pack4(acc);
        }
      }
    }
    __syncthreads();

    // attn_out: x += A2 @ Wao^T + b (weights shared)
    {
      bf16x8 ba[2][2][2];
#pragma unroll
      for (int G = 0; G < 2; G++)
#pragma unroll
        for (int nt = 0; nt < 2; nt++)
#pragma unroll
          for (int kt = 0; kt < 2; kt++)
            ba[G][nt][kt] = *(const bf16x8*)&A2[G][(nt * 16 + lr) * 72 + kt * 32 + hi * 8];
      const unsigned short* Wo = aow_b + ly * 64 * 64;
      const float* Bo = aob + ly * 64;
#pragma unroll
      for (int mi = 0; mi < 2; mi++) {
        int mt = w + mi * 2;
        bf16x8 a0 = *(const bf16x8*)(Wo + (mt * 16 + lr) * 64 + hi * 8);
        bf16x8 a1 = *(const bf16x8*)(Wo + (mt * 16 + lr) * 64 + 32 + hi * 8);
        float4 b4 = *(const float4*)(Bo + mt * 16 + hi * 4);
#pragma unroll
        for (int G = 0; G < 2; G++)
#pragma unroll
          for (int nt = 0; nt < 2; nt++) {
            f32x4 acc; acc[0] = b4.x; acc[1] = b4.y; acc[2] = b4.z; acc[3] = b4.w;
            acc = mfma16(a0, ba[G][nt][0], acc);
            acc = mfma16(a1, ba[G][nt][1], acc);
            x[G][nt][mi] += acc;
          }
      }
    }
    // (no barrier: LN2's publish barrier protects A2 reads)

    LN(ln2_g + ly*64, ln2_b + ly*64);

    // ff1: F[t][o] = relu(S @ W1^T + b1) (weights shared)
    {
      bf16x8 bs[2][2][2];
#pragma unroll
      for (int G = 0; G < 2; G++)
#pragma unroll
        for (int nt = 0; nt < 2; nt++)
#pragma unroll
          for (int kt = 0; kt < 2; kt++)
            bs[G][nt][kt] = *(const bf16x8*)&S[G][(nt * 16 + lr) * 72 + kt * 32 + hi * 8];
      const unsigned short* W1 = f1w_b + ly * 128 * 64;
      const float* B1 = f1b + ly * 128;
#pragma unroll
      for (int mi = 0; mi < 4; mi++) {
        int mt = w + mi * 2;
        bf16x8 a0 = *(const bf16x8*)(W1 + (mt * 16 + lr) * 64 + hi * 8);
        bf16x8 a1 = *(const bf16x8*)(W1 + (mt * 16 + lr) * 64 + 32 + hi * 8);
        float4 b4 = *(const float4*)(B1 + mt * 16 + hi * 4);
#pragma unroll
        for (int G = 0; G < 2; G++)
#pragma unroll
          for (int nt = 0; nt < 2; nt++) {
            f32x4 acc; acc[0] = b4.x; acc[1] = b4.y; acc[2] = b4.z; acc[3] = b4.w;
            acc = mfma16(a0, bs[G][nt][0], acc);
            acc = mfma16(a1, bs[G][nt][1], acc);
#pragma unroll
            for (int r = 0; r < 4; r++) acc[r] = fmaxf(acc[r], 0.f);
            *(bf16x4*)&Fb[G][(nt * 16 + lr) * 136 + mt * 16 + hi * 4] = pack4(acc);
          }
      }
    }
    __syncthreads();

    // ff2: x += F @ W2^T + b2 (weights shared)
    {
      bf16x8 bfr[2][2][4];
#pragma unroll
      for (int G = 0; G < 2; G++)
#pragma unroll
        for (int nt = 0; nt < 2; nt++)
#pragma unroll
          for (int kt = 0; kt < 4; kt++)
            bfr[G][nt][kt] = *(const bf16x8*)&Fb[G][(nt * 16 + lr) * 136 + kt * 32 + hi * 8];
      const unsigned short* W2 = f2w_b + ly * 64 * 128;
      const float* B2 = f2b + ly * 64;
#pragma unroll
      for (int mi = 0; mi < 2; mi++) {
        int mt = w + mi * 2;
        bf16x8 a[4];
#pragma unroll
        for (int kt = 0; kt < 4; kt++)
          a[kt] = *(const bf16x8*)(W2 + (mt * 16 + lr) * 128 + kt * 32 + hi * 8);
        float4 b4 = *(const float4*)(B2 + mt * 16 + hi * 4);
#pragma unroll
        for (int G = 0; G < 2; G++)
#pragma unroll
          for (int nt = 0; nt < 2; nt++) {
            f32x4 acc; acc[0] = b4.x; acc[1] = b4.y; acc[2] = b4.z; acc[3] = b4.w;
#pragma unroll
            for (int kt = 0; kt < 4; kt++) acc = mfma16(a[kt], bfr[G][nt][kt], acc);
            x[G][nt][mi] += acc;
          }
      }
    }
    // (no barrier: next LN1's publish barrier protects F reads)
  }

  // ---- max pool: register shuffle tree per group -> part[G] ----
#pragma unroll
  for (int G = 0; G < 2; G++) {
    f32x4 pm[2];
#pragma unroll
    for (int mi = 0; mi < 2; mi++)
#pragma unroll
      for (int r = 0; r < 4; r++) pm[mi][r] = fmaxf(x[G][0][mi][r], x[G][1][mi][r]);
#pragma unroll
    for (int d = 1; d < 16; d <<= 1)
#pragma unroll
      for (int mi = 0; mi < 2; mi++)
#pragma unroll
        for (int r = 0; r < 4; r++) pm[mi][r] = fmaxf(pm[mi][r], __shfl_xor(pm[mi][r], d));
    if (lr == 0) {
#pragma unroll
      for (int mi = 0; mi < 2; mi++) {
        int mt = w + mi * 2;
        *(f32x4*)&part[G][mt * 16 + hi * 4] = pm[mi];
      }
    }
  }
  __syncthreads();

  // ---- output projection: out_w row loaded once, used for both groups ----
  {
    int o = tid;
    const float* wr = out_w + o * 64;
    float a0[2] = {0.f, 0.f}, a1[2] = {0.f, 0.f}, a2[2] = {0.f, 0.f}, a3[2] = {0.f, 0.f};
#pragma unroll
    for (int i = 0; i < 16; i++) {
      float4 wv = *(const float4*)(wr + i * 4);
#pragma unroll
      for (int G = 0; G < 2; G++) {
        float4 pv = *(const float4*)&part[G][i * 4];
        a0[G] = fmaf(pv.x, wv.x, a0[G]);
        a1[G] = fmaf(pv.y, wv.y, a1[G]);
        a2[G] = fmaf(pv.z, wv.z, a2[G]);
        a3[G] = fmaf(pv.w, wv.w, a3[G]);
      }
    }
    float ob = out_b[o];
#pragma unroll
    for (int G = 0; G < 2; G++)
      out[(size_t)mg[G] * OUTD + o] = ob + (a0[G] + a1[G]) + (a2[G] + a3[G]);
  }
}

extern "C" void kernel_launch(void* const* d_in, const int* in_sizes, int n_in,
                              void* d_out, int out_size, void* d_ws, size_t ws_size,
                              hipStream_t stream) {
  const float* xyz         = (const float*)d_in[0];
  const float* new_xyz     = (const float*)d_in[1];
  const float* features    = (const float*)d_in[2];
  const int*   group_idx   = (const int*)d_in[3];
  const unsigned char* empty_mask = (const unsigned char*)d_in[4];
  const float* pos_w1      = (const float*)d_in[5];
  const float* pos_bn_g    = (const float*)d_in[6];
  const float* pos_bn_b    = (const float*)d_in[7];
  const float* pos_bn_mean = (const float*)d_in[8];
  const float* pos_bn_var  = (const float*)d_in[9];
  const float* pos_w2      = (const float*)d_in[10];
  const float* pos_b2      = (const float*)d_in[11];
  const float* ln1_g       = (const float*)d_in[12];
  const float* ln1_b       = (const float*)d_in[13];
  const float* qkv_w       = (const float*)d_in[14];
  const float* qkv_b       = (const float*)d_in[15];
  const float* aow         = (const float*)d_in[16];
  const float* aob         = (const float*)d_in[17];
  const float* ln2_g       = (const float*)d_in[18];
  const float* ln2_b       = (const float*)d_in[19];
  const float* f1w         = (const float*)d_in[20];
  const float* f1b         = (const float*)d_in[21];
  const float* f2w         = (const float*)d_in[22];
  const float* f2b         = (const float*)d_in[23];
  const float* out_w       = (const float*)d_in[24];
  const float* out_b       = (const float*)d_in[25];
  float* out = (float*)d_out;
  unsigned char* ws = (unsigned char*)d_ws;

  hipLaunchKernelGGL(convert_weights, dim3(265), dim3(256), 0, stream,
                     qkv_w, aow, f1w, f2w, pos_w2, pos_w1,
                     pos_bn_g, pos_bn_b, pos_bn_mean, pos_bn_var, ws);

  hipLaunchKernelGGL(nvt_mfma, dim3(MQ / 2), dim3(128), 0, stream,
                     xyz, new_xyz, features, group_idx, empty_mask,
                     pos_b2, ln1_g, ln1_b, qkv_b, aob, ln2_g, ln2_b,
                     f1b, f2b, out_w, out_b, ws, out);
}